// Round 5
// baseline (602.956 us; speedup 1.0000x reference)
//
#include <hip/hip_runtime.h>
#include <math.h>

// Problem constants
#define BB 16
#define CC 256
#define HH 128
#define WW 128
#define HWSZ 16384        // H*W
#define NF 8
#define EPSV 1e-5f

typedef __attribute__((ext_vector_type(8))) short short8;   // 8 bf16 = 4 VGPRs
typedef __attribute__((ext_vector_type(4))) float f32x4;

static __device__ __forceinline__ unsigned short f2bf(float f) {
  unsigned int u = __float_as_uint(f);
  u += 0x7fffu + ((u >> 16) & 1u);       // round-to-nearest-even
  return (unsigned short)(u >> 16);
}

static __device__ __forceinline__ float bf2f(unsigned int h) {
  return __uint_as_float(h << 16);
}

// ---------------------------------------------------------------------------
// K0: pack proj_w [o][c] fp32 -> bf16 in MFMA A-fragment order:
//     ap[((MB*8+kb)*64+lane)*8+e] = w[MB*16+(lane&15)][kb*32+(lane>>4)*8+e]
// ---------------------------------------------------------------------------
__global__ __launch_bounds__(256) void pack_a_kernel(
    const float* __restrict__ pw, unsigned short* __restrict__ ap) {
  int idx = blockIdx.x * 256 + threadIdx.x;     // 0..65535
  int e = idx & 7;
  int lane = (idx >> 3) & 63;
  int kb = (idx >> 9) & 7;
  int mb = idx >> 12;
  int o = mb * 16 + (lane & 15);
  int c = kb * 32 + (lane >> 4) * 8 + e;
  ap[idx] = f2bf(pw[o * 256 + c]);
}

// ---------------------------------------------------------------------------
// K1: pooled[b,c] = mean over HW.  One block per (b,c) plane.
// ---------------------------------------------------------------------------
__global__ __launch_bounds__(256) void pool_kernel(
    const float* __restrict__ x, float* __restrict__ pooled) {
  int plane = blockIdx.x;
  const float4* xp = (const float4*)(x + (size_t)plane * HWSZ);
  int tid = threadIdx.x;
  float s = 0.f;
#pragma unroll
  for (int i = 0; i < 16; ++i) {
    float4 v = xp[tid + i * 256];
    s += v.x + v.y + v.z + v.w;
  }
#pragma unroll
  for (int off = 32; off > 0; off >>= 1) s += __shfl_down(s, off, 64);
  __shared__ float ls[4];
  if ((tid & 63) == 0) ls[tid >> 6] = s;
  __syncthreads();
  if (tid == 0) pooled[plane] = (ls[0] + ls[1] + ls[2] + ls[3]) * (1.0f / 16384.0f);
}

// ---------------------------------------------------------------------------
// K2: selector: GAP -> linear -> softmax -> mix filter bank; zero GN stats.
// ---------------------------------------------------------------------------
__global__ __launch_bounds__(256) void selector_kernel(
    const float* __restrict__ pooled, const float* __restrict__ sel_w,
    const float* __restrict__ sel_b, const float* __restrict__ fbank,
    float* __restrict__ combined, float* __restrict__ stats) {
  int tid = threadIdx.x;
  stats[tid] = 0.f;  // 256 slots: [0..127] sum, [128..255] sumsq
  __shared__ float lg[BB][NF];
  __shared__ float wsm[BB][NF];
  if (tid < BB * NF) {
    int b = tid >> 3, n = tid & 7;
    const float* p = pooled + b * CC;
    const float* w = sel_w + n * CC;
    float d = sel_b[n];
    for (int c = 0; c < CC; c += 4) {
      d += p[c] * w[c] + p[c + 1] * w[c + 1] + p[c + 2] * w[c + 2] + p[c + 3] * w[c + 3];
    }
    lg[b][n] = d;
  }
  __syncthreads();
  if (tid < BB) {
    int b = tid;
    float m = lg[b][0];
#pragma unroll
    for (int n = 1; n < NF; ++n) m = fmaxf(m, lg[b][n]);
    float e[NF];
    float s = 0.f;
#pragma unroll
    for (int n = 0; n < NF; ++n) { e[n] = expf(lg[b][n] - m); s += e[n]; }
    float inv = 1.0f / s;
#pragma unroll
    for (int n = 0; n < NF; ++n) wsm[b][n] = e[n] * inv;
  }
  __syncthreads();
  for (int i = tid; i < BB * 49; i += 256) {
    int b = i / 49, j = i % 49;
    float acc = 0.f;
#pragma unroll
    for (int n = 0; n < NF; ++n) acc += wsm[b][n] * fbank[n * 49 + j];
    combined[b * 64 + j] = acc;
  }
}

// ---------------------------------------------------------------------------
// K3: depthwise 7x7 conv, per-sample filter; fp32 compute, bf16 output.
// ---------------------------------------------------------------------------
#define TR 32
__global__ __launch_bounds__(256) void dwconv_kernel(
    const float* __restrict__ x, const float* __restrict__ combined,
    unsigned short* __restrict__ fbp) {
  int plane = blockIdx.x;          // b*256 + c
  int rt = blockIdx.y;             // 0..3
  int b = plane >> 8;
  int r0 = rt * TR;
  int tid = threadIdx.x;

  __shared__ float xs[TR + 6][136];

  float kf[49];
  {
    const float* cb = combined + b * 64;
#pragma unroll
    for (int i = 0; i < 49; ++i) kf[i] = cb[i];
  }

  const size_t pbase = (size_t)plane * HWSZ;
  for (int idx = tid; idx < (TR + 6) * 34; idx += 256) {
    int row = idx / 34;
    int seg = idx % 34;
    int r = r0 - 3 + row;
    int c = seg * 4 - 4;
    float4 v = make_float4(0.f, 0.f, 0.f, 0.f);
    if (r >= 0 && r < HH && c >= 0 && c < WW) {
      v = *(const float4*)(x + pbase + (size_t)r * WW + c);
    }
    *(float4*)&xs[row][seg * 4] = v;
  }
  __syncthreads();

  int cg = tid & 31;
  int rg = tid >> 5;
  float acc[4][4] = {};

#pragma unroll
  for (int ri = 0; ri < 10; ++ri) {
    int lrow = 4 * rg + ri;
    float xr[12];
#pragma unroll
    for (int s = 0; s < 3; ++s)
      *(float4*)&xr[4 * s] = *(const float4*)&xs[lrow][cg * 4 + 4 * s];
#pragma unroll
    for (int orr = 0; orr < 4; ++orr) {
      int dy = ri - orr;
      if (dy < 0 || dy > 6) continue;
#pragma unroll
      for (int oc = 0; oc < 4; ++oc) {
#pragma unroll
        for (int dx = 0; dx < 7; ++dx) {
          acc[orr][oc] += xr[oc + dx + 1] * kf[dy * 7 + dx];
        }
      }
    }
  }

#pragma unroll
  for (int orr = 0; orr < 4; ++orr) {
    ushort4 sv;
    sv.x = f2bf(acc[orr][0]);
    sv.y = f2bf(acc[orr][1]);
    sv.z = f2bf(acc[orr][2]);
    sv.w = f2bf(acc[orr][3]);
    *(ushort4*)(fbp + pbase + (size_t)(r0 + 4 * rg + orr) * WW + 4 * cg) = sv;
  }
}

// ---------------------------------------------------------------------------
// K3.5: transpose fb[b][c][p] -> fbT[b][p][c].  Tile = 64c x 64p, 256 thr.
//       LDS as uint[64p][33] (c-pairs, stride 33 -> 2-way-free banks).
// ---------------------------------------------------------------------------
__global__ __launch_bounds__(256) void transpose_kernel(
    const unsigned short* __restrict__ fb, unsigned short* __restrict__ fbT) {
  int bid = blockIdx.x;            // 16 b * 4 cstripe * 256 pstripe
  int bs = bid >> 10;
  int cs = (bid >> 8) & 3;
  int ps = bid & 255;
  int t = threadIdx.x;

  __shared__ unsigned int Ts[64][33];

  int cpair = t >> 3;              // 0..31 -> c rows {2cp, 2cp+1}
  int pch = t & 7;                 // 0..7  -> p chunk of 8
  const unsigned short* s =
      fb + ((size_t)bs * CC + cs * 64 + 2 * cpair) * HWSZ + ps * 64 + pch * 8;
  uint4 A0 = *(const uint4*)s;
  uint4 A1 = *(const uint4*)(s + HWSZ);
  unsigned int wa[4] = {A0.x, A0.y, A0.z, A0.w};
  unsigned int wb[4] = {A1.x, A1.y, A1.z, A1.w};
#pragma unroll
  for (int i = 0; i < 8; ++i) {
    int p = pch * 8 + i;
    unsigned int lo = (wa[i >> 1] >> ((i & 1) * 16)) & 0xffffu;
    unsigned int hi = (wb[i >> 1] >> ((i & 1) * 16)) & 0xffffu;
    Ts[p][cpair] = lo | (hi << 16);
  }
  __syncthreads();

  size_t obase = ((size_t)bs * HWSZ + (size_t)ps * 64) * 256 + cs * 64;
#pragma unroll
  for (int r = 0; r < 2; ++r) {
    int chunk = t + 256 * r;
    int p = chunk >> 3, ch = chunk & 7;   // row p, c-chunk of 8 (4 uints)
    uint4 v;
    v.x = Ts[p][ch * 4];
    v.y = Ts[p][ch * 4 + 1];
    v.z = Ts[p][ch * 4 + 2];
    v.w = Ts[p][ch * 4 + 3];
    *(uint4*)(fbT + obase + (size_t)p * 256 + ch * 8) = v;
  }
}

// ---------------------------------------------------------------------------
// K4: 1x1 conv as bf16 MFMA GEMM, barrier-free:
//     y[b,o,p] = sum_c W[o][c]*F[b][c][p] + pb[o]
//     Block = 256 o x 64 p; 4 independent waves, each 64o x 64p (4x4 MFMA).
//     A-frags from packed ap (L2-hot); B-frags DIRECT dwordx4 from fbT[p][c]
//     (same fragment semantics as r2/r4's proven LDS read). Reg double-buffer
//     both operands; no LDS in main loop. Epilogue: LDS bounce -> coalesced
//     16B stores of bf16 y, plus GN partial sums (atomics).
// ---------------------------------------------------------------------------
__global__ __launch_bounds__(256, 3) void gemm_kernel(
    const unsigned short* __restrict__ fbT, const unsigned short* __restrict__ ap,
    const float* __restrict__ proj_b, unsigned short* __restrict__ yb,
    float* __restrict__ stats) {
  int bid = blockIdx.x;
  int bs = bid >> 8;               // sample
  int pt = bid & 255;              // pixel tile (64 wide)
  int p0 = pt * 64;
  int tid = threadIdx.x;
  int lane = tid & 63;
  int wave = tid >> 6;             // 0..3 -> o rows wave*64..+63

  __shared__ unsigned short yt[4][64][72];   // epilogue bounce, wave-private

  // A fragment base: MB = wave*4 + mb ; frag(mb,kb) = apl + mb*4096 + kb*512
  const unsigned short* apl = ap + (size_t)(wave * 4) * 4096 + lane * 8;
  // B fragment base: frag(nb,kb) = bpl + nb*16*256 + kb*32
  const unsigned short* bpl =
      fbT + ((size_t)bs * HWSZ + p0 + (lane & 15)) * 256 + (lane >> 4) * 8;

  f32x4 acc[4][4];
#pragma unroll
  for (int mb = 0; mb < 4; ++mb)
#pragma unroll
    for (int nb = 0; nb < 4; ++nb) acc[mb][nb] = (f32x4){0.f, 0.f, 0.f, 0.f};

  short8 af[4], afn[4], bf[4], bfn[4];
#pragma unroll
  for (int mb = 0; mb < 4; ++mb) af[mb] = *(const short8*)(apl + mb * 4096);
#pragma unroll
  for (int nb = 0; nb < 4; ++nb) bf[nb] = *(const short8*)(bpl + nb * 4096);

#pragma unroll
  for (int kb = 0; kb < 8; ++kb) {
    if (kb < 7) {
#pragma unroll
      for (int mb = 0; mb < 4; ++mb)
        afn[mb] = *(const short8*)(apl + mb * 4096 + (kb + 1) * 512);
#pragma unroll
      for (int nb = 0; nb < 4; ++nb)
        bfn[nb] = *(const short8*)(bpl + nb * 4096 + (kb + 1) * 32);
    }
#pragma unroll
    for (int mb = 0; mb < 4; ++mb)
#pragma unroll
      for (int nb = 0; nb < 4; ++nb)
        acc[mb][nb] = __builtin_amdgcn_mfma_f32_16x16x32_bf16(
            af[mb], bf[nb], acc[mb][nb], 0, 0, 0);
    if (kb < 7) {
#pragma unroll
      for (int mb = 0; mb < 4; ++mb) af[mb] = afn[mb];
#pragma unroll
      for (int nb = 0; nb < 4; ++nb) bf[nb] = bfn[nb];
    }
  }

  // ---- epilogue
  // C/D layout: col(p) = lane&15, row(o) = (lane>>4)*4 + reg
  float psum[2] = {0.f, 0.f}, psq[2] = {0.f, 0.f};
  int orl = (lane >> 4) * 4;
  int pl = lane & 15;
#pragma unroll
  for (int mb = 0; mb < 4; ++mb) {
    int gi = mb >> 1;
#pragma unroll
    for (int r = 0; r < 4; ++r) {
      int ol = mb * 16 + orl + r;
      float pb = proj_b[wave * 64 + ol];
#pragma unroll
      for (int nb = 0; nb < 4; ++nb) {
        float v = acc[mb][nb][r] + pb;
        yt[wave][ol][pl + nb * 16] = f2bf(v);
        psum[gi] += v;
        psq[gi] += v * v;
      }
    }
  }
  __syncthreads();   // make bounce visible (cross-lane within wave)

  // coalesced y store: 8 chunks/lane, lanes 0..7 = one full 128B row span
  const size_t ybase = (size_t)bs * CC * HWSZ + p0;
#pragma unroll
  for (int k = 0; k < 8; ++k) {
    int idx = k * 64 + lane;
    int ol = idx >> 3, ch = idx & 7;
    uint4 v = *(const uint4*)&yt[wave][ol][ch * 8];
    *(uint4*)(yb + ybase + (size_t)(wave * 64 + ol) * HWSZ + ch * 8) = v;
  }

#pragma unroll
  for (int off = 32; off > 0; off >>= 1) {
#pragma unroll
    for (int k = 0; k < 2; ++k) {
      psum[k] += __shfl_down(psum[k], off, 64);
      psq[k] += __shfl_down(psq[k], off, 64);
    }
  }
  if (lane == 0) {
    int gb = bs * 8 + wave * 2;    // wave covers 2 GN groups (64 ch)
    atomicAdd(&stats[gb], psum[0]);
    atomicAdd(&stats[gb + 1], psum[1]);
    atomicAdd(&stats[128 + gb], psq[0]);
    atomicAdd(&stats[128 + gb + 1], psq[1]);
  }
}

// ---------------------------------------------------------------------------
// K5: GroupNorm affine + exact GELU + residual. Reads bf16 y, writes fp32 out.
// ---------------------------------------------------------------------------
__global__ __launch_bounds__(256) void out_kernel(
    const float* __restrict__ x, const unsigned short* __restrict__ yb,
    const float* __restrict__ stats, const float* __restrict__ gamma,
    const float* __restrict__ beta, float* __restrict__ out) {
  int plane = blockIdx.x;
  int b = plane >> 8, c = plane & 255, g = c >> 5;
  const float inv_n = 1.0f / (32.0f * (float)HWSZ);
  float mean = stats[b * 8 + g] * inv_n;
  float var = stats[128 + b * 8 + g] * inv_n - mean * mean;
  float rstd = rsqrtf(var + EPSV);
  float scale = gamma[c] * rstd;
  float shift = beta[c] - mean * scale;

  const size_t base = (size_t)plane * HWSZ;
  for (int i = threadIdx.x; i < HWSZ / 8; i += 256) {
    uint4 yv = *(const uint4*)(yb + base + 8 * (size_t)i);
    float4 x0 = *(const float4*)(x + base + 8 * (size_t)i);
    float4 x1 = *(const float4*)(x + base + 8 * (size_t)i + 4);
    unsigned int yw[4] = {yv.x, yv.y, yv.z, yv.w};
    float r[8];
    float xr[8] = {x0.x, x0.y, x0.z, x0.w, x1.x, x1.y, x1.z, x1.w};
#pragma unroll
    for (int k = 0; k < 8; ++k) {
      unsigned int h = (yw[k >> 1] >> ((k & 1) * 16)) & 0xffffu;
      float t = bf2f(h) * scale + shift;
      float ge = 0.5f * t * (1.0f + erff(t * 0.70710678118654752f));
      r[k] = ge + xr[k];
    }
    *(float4*)(out + base + 8 * (size_t)i) = make_float4(r[0], r[1], r[2], r[3]);
    *(float4*)(out + base + 8 * (size_t)i + 4) = make_float4(r[4], r[5], r[6], r[7]);
  }
}

// ---------------------------------------------------------------------------
extern "C" void kernel_launch(void* const* d_in, const int* in_sizes, int n_in,
                              void* d_out, int out_size, void* d_ws, size_t ws_size,
                              hipStream_t stream) {
  const float* x      = (const float*)d_in[0];
  const float* fbank  = (const float*)d_in[1];   // [NF,1,7,7]
  const float* sel_w  = (const float*)d_in[2];   // [NF,C]
  const float* sel_b  = (const float*)d_in[3];   // [NF]
  const float* proj_w = (const float*)d_in[4];   // [C,C,1,1]
  const float* proj_b = (const float*)d_in[5];   // [C]
  const float* gamma  = (const float*)d_in[6];   // [C]
  const float* beta   = (const float*)d_in[7];   // [C]
  float* out = (float*)d_out;

  // ws layout: buf0 bf16 [B*C*HW] (fb, later reused as yb) |
  //            buf1 bf16 [B*C*HW] (fbT) | ap bf16 [65536] | f32 smalls
  unsigned short* fb  = (unsigned short*)d_ws;   // dwconv out; dead after transpose
  unsigned short* yb  = fb;                      // gemm y output reuses fb space
  unsigned short* fbT = fb + (size_t)BB * CC * HWSZ;
  unsigned short* apk = fbT + (size_t)BB * CC * HWSZ;
  float* pooled   = (float*)(apk + 65536);
  float* combined = pooled + BB * CC;
  float* stats    = combined + BB * 64;

  hipLaunchKernelGGL(pack_a_kernel, dim3(256), dim3(256), 0, stream, proj_w, apk);
  hipLaunchKernelGGL(pool_kernel, dim3(BB * CC), dim3(256), 0, stream, x, pooled);
  hipLaunchKernelGGL(selector_kernel, dim3(1), dim3(256), 0, stream,
                     pooled, sel_w, sel_b, fbank, combined, stats);
  hipLaunchKernelGGL(dwconv_kernel, dim3(BB * CC, HH / TR), dim3(256), 0, stream,
                     x, combined, fb);
  hipLaunchKernelGGL(transpose_kernel, dim3(BB * 4 * 256), dim3(256), 0, stream,
                     fb, fbT);
  hipLaunchKernelGGL(gemm_kernel, dim3(BB * 256), dim3(256), 0, stream,
                     fbT, apk, proj_b, yb, stats);
  hipLaunchKernelGGL(out_kernel, dim3(BB * CC), dim3(256), 0, stream,
                     x, yb, stats, gamma, beta, out);
}

// Round 6
// 566.546 us; speedup vs baseline: 1.0643x; 1.0643x over previous
//
#include <hip/hip_runtime.h>
#include <math.h>

// Problem constants
#define BB 16
#define CC 256
#define HH 128
#define WW 128
#define HWSZ 16384        // H*W
#define NF 8
#define EPSV 1e-5f

typedef __attribute__((ext_vector_type(8))) short short8;   // 8 bf16 = 4 VGPRs
typedef __attribute__((ext_vector_type(4))) float f32x4;

static __device__ __forceinline__ unsigned short f2bf(float f) {
  unsigned int u = __float_as_uint(f);
  u += 0x7fffu + ((u >> 16) & 1u);       // round-to-nearest-even
  return (unsigned short)(u >> 16);
}

static __device__ __forceinline__ float bf2f(unsigned int h) {
  return __uint_as_float(h << 16);
}

static __device__ __forceinline__ void gload_lds16(const unsigned short* g,
                                                   unsigned short* l) {
  __builtin_amdgcn_global_load_lds(
      (const __attribute__((address_space(1))) void*)(size_t)g,
      (__attribute__((address_space(3))) void*)(unsigned)(size_t)l, 16, 0, 0);
}

// ---------------------------------------------------------------------------
// K0: pack proj_w [o][c] fp32 -> bf16 in MFMA A-fragment order:
//     ap[((MB*8+kb)*64+lane)*8+e] = w[MB*16+(lane&15)][kb*32+(lane>>4)*8+e]
// ---------------------------------------------------------------------------
__global__ __launch_bounds__(256) void pack_a_kernel(
    const float* __restrict__ pw, unsigned short* __restrict__ ap) {
  int idx = blockIdx.x * 256 + threadIdx.x;     // 0..65535
  int e = idx & 7;
  int lane = (idx >> 3) & 63;
  int kb = (idx >> 9) & 7;
  int mb = idx >> 12;
  int o = mb * 16 + (lane & 15);
  int c = kb * 32 + (lane >> 4) * 8 + e;
  ap[idx] = f2bf(pw[o * 256 + c]);
}

// ---------------------------------------------------------------------------
// K1: pooled[b,c] = mean over HW.  One block per (b,c) plane.
// ---------------------------------------------------------------------------
__global__ __launch_bounds__(256) void pool_kernel(
    const float* __restrict__ x, float* __restrict__ pooled) {
  int plane = blockIdx.x;
  const float4* xp = (const float4*)(x + (size_t)plane * HWSZ);
  int tid = threadIdx.x;
  float s = 0.f;
#pragma unroll
  for (int i = 0; i < 16; ++i) {
    float4 v = xp[tid + i * 256];
    s += v.x + v.y + v.z + v.w;
  }
#pragma unroll
  for (int off = 32; off > 0; off >>= 1) s += __shfl_down(s, off, 64);
  __shared__ float ls[4];
  if ((tid & 63) == 0) ls[tid >> 6] = s;
  __syncthreads();
  if (tid == 0) pooled[plane] = (ls[0] + ls[1] + ls[2] + ls[3]) * (1.0f / 16384.0f);
}

// ---------------------------------------------------------------------------
// K2: selector: GAP -> linear -> softmax -> mix filter bank; zero GN stats.
// ---------------------------------------------------------------------------
__global__ __launch_bounds__(256) void selector_kernel(
    const float* __restrict__ pooled, const float* __restrict__ sel_w,
    const float* __restrict__ sel_b, const float* __restrict__ fbank,
    float* __restrict__ combined, float* __restrict__ stats) {
  int tid = threadIdx.x;
  stats[tid] = 0.f;  // 256 slots: [0..127] sum, [128..255] sumsq
  __shared__ float lg[BB][NF];
  __shared__ float wsm[BB][NF];
  if (tid < BB * NF) {
    int b = tid >> 3, n = tid & 7;
    const float* p = pooled + b * CC;
    const float* w = sel_w + n * CC;
    float d = sel_b[n];
    for (int c = 0; c < CC; c += 4) {
      d += p[c] * w[c] + p[c + 1] * w[c + 1] + p[c + 2] * w[c + 2] + p[c + 3] * w[c + 3];
    }
    lg[b][n] = d;
  }
  __syncthreads();
  if (tid < BB) {
    int b = tid;
    float m = lg[b][0];
#pragma unroll
    for (int n = 1; n < NF; ++n) m = fmaxf(m, lg[b][n]);
    float e[NF];
    float s = 0.f;
#pragma unroll
    for (int n = 0; n < NF; ++n) { e[n] = expf(lg[b][n] - m); s += e[n]; }
    float inv = 1.0f / s;
#pragma unroll
    for (int n = 0; n < NF; ++n) wsm[b][n] = e[n] * inv;
  }
  __syncthreads();
  for (int i = tid; i < BB * 49; i += 256) {
    int b = i / 49, j = i % 49;
    float acc = 0.f;
#pragma unroll
    for (int n = 0; n < NF; ++n) acc += wsm[b][n] * fbank[n * 49 + j];
    combined[b * 64 + j] = acc;
  }
}

// ---------------------------------------------------------------------------
// K3: depthwise 7x7 conv, per-sample filter; fp32 compute, bf16 output.
// ---------------------------------------------------------------------------
#define TR 32
__global__ __launch_bounds__(256) void dwconv_kernel(
    const float* __restrict__ x, const float* __restrict__ combined,
    unsigned short* __restrict__ fbp) {
  int plane = blockIdx.x;          // b*256 + c
  int rt = blockIdx.y;             // 0..3
  int b = plane >> 8;
  int r0 = rt * TR;
  int tid = threadIdx.x;

  __shared__ float xs[TR + 6][136];

  float kf[49];
  {
    const float* cb = combined + b * 64;
#pragma unroll
    for (int i = 0; i < 49; ++i) kf[i] = cb[i];
  }

  const size_t pbase = (size_t)plane * HWSZ;
  for (int idx = tid; idx < (TR + 6) * 34; idx += 256) {
    int row = idx / 34;
    int seg = idx % 34;
    int r = r0 - 3 + row;
    int c = seg * 4 - 4;
    float4 v = make_float4(0.f, 0.f, 0.f, 0.f);
    if (r >= 0 && r < HH && c >= 0 && c < WW) {
      v = *(const float4*)(x + pbase + (size_t)r * WW + c);
    }
    *(float4*)&xs[row][seg * 4] = v;
  }
  __syncthreads();

  int cg = tid & 31;
  int rg = tid >> 5;
  float acc[4][4] = {};

#pragma unroll
  for (int ri = 0; ri < 10; ++ri) {
    int lrow = 4 * rg + ri;
    float xr[12];
#pragma unroll
    for (int s = 0; s < 3; ++s)
      *(float4*)&xr[4 * s] = *(const float4*)&xs[lrow][cg * 4 + 4 * s];
#pragma unroll
    for (int orr = 0; orr < 4; ++orr) {
      int dy = ri - orr;
      if (dy < 0 || dy > 6) continue;
#pragma unroll
      for (int oc = 0; oc < 4; ++oc) {
#pragma unroll
        for (int dx = 0; dx < 7; ++dx) {
          acc[orr][oc] += xr[oc + dx + 1] * kf[dy * 7 + dx];
        }
      }
    }
  }

#pragma unroll
  for (int orr = 0; orr < 4; ++orr) {
    ushort4 sv;
    sv.x = f2bf(acc[orr][0]);
    sv.y = f2bf(acc[orr][1]);
    sv.z = f2bf(acc[orr][2]);
    sv.w = f2bf(acc[orr][3]);
    *(ushort4*)(fbp + pbase + (size_t)(r0 + 4 * rg + orr) * WW + 4 * cg) = sv;
  }
}

// ---------------------------------------------------------------------------
// K3.5: transpose fb[b][c][p] -> fbT[b][p][c].  Tile = 64c x 64p, 256 thr.
//       (proven round 5)
// ---------------------------------------------------------------------------
__global__ __launch_bounds__(256) void transpose_kernel(
    const unsigned short* __restrict__ fb, unsigned short* __restrict__ fbT) {
  int bid = blockIdx.x;            // 16 b * 4 cstripe * 256 pstripe
  int bs = bid >> 10;
  int cs = (bid >> 8) & 3;
  int ps = bid & 255;
  int t = threadIdx.x;

  __shared__ unsigned int Ts[64][33];

  int cpair = t >> 3;              // 0..31 -> c rows {2cp, 2cp+1}
  int pch = t & 7;                 // 0..7  -> p chunk of 8
  const unsigned short* s =
      fb + ((size_t)bs * CC + cs * 64 + 2 * cpair) * HWSZ + ps * 64 + pch * 8;
  uint4 A0 = *(const uint4*)s;
  uint4 A1 = *(const uint4*)(s + HWSZ);
  unsigned int wa[4] = {A0.x, A0.y, A0.z, A0.w};
  unsigned int wb[4] = {A1.x, A1.y, A1.z, A1.w};
#pragma unroll
  for (int i = 0; i < 8; ++i) {
    int p = pch * 8 + i;
    unsigned int lo = (wa[i >> 1] >> ((i & 1) * 16)) & 0xffffu;
    unsigned int hi = (wb[i >> 1] >> ((i & 1) * 16)) & 0xffffu;
    Ts[p][cpair] = lo | (hi << 16);
  }
  __syncthreads();

  size_t obase = ((size_t)bs * HWSZ + (size_t)ps * 64) * 256 + cs * 64;
#pragma unroll
  for (int r = 0; r < 2; ++r) {
    int chunk = t + 256 * r;
    int p = chunk >> 3, ch = chunk & 7;   // row p, c-chunk of 8 (4 uints)
    uint4 v;
    v.x = Ts[p][ch * 4];
    v.y = Ts[p][ch * 4 + 1];
    v.z = Ts[p][ch * 4 + 2];
    v.w = Ts[p][ch * 4 + 3];
    *(uint4*)(fbT + obase + (size_t)p * 256 + ch * 8) = v;
  }
}

// ---------------------------------------------------------------------------
// K4: 1x1 conv as bf16 MFMA GEMM with whole-panel preload + counted vmcnt:
//     y[b,o,p] = sum_c W[o][c]*F[b][c][p] + pb[o]
//     Block = 256 o x 64 p, 512 thr (8 waves, each 32o x 64p = 2x4 MFMA).
//     Prologue: ALL 16 A-frags (L2-hot) then ALL 8 B-subtiles via
//     global_load_lds (linear dest, r4-proven swizzle pre-applied on source).
//     Phase kb: s_waitcnt vmcnt(3-(kb>>1)) + s_barrier -> ds_read -> 8 MFMA.
//     Single-buffered panel (read-only -> no WAR, 1 barrier/phase).
//     Epilogue: LDS bounce (unions the panel) -> coalesced bf16 y stores +
//     GN partial sums (wave == one GN group).
// ---------------------------------------------------------------------------
#define SWZ(p) ((((p) >> 1) ^ ((p) >> 4)) & 3)

__global__ __launch_bounds__(512, 4) void gemm_kernel(
    const unsigned short* __restrict__ fbT, const unsigned short* __restrict__ ap,
    const float* __restrict__ proj_b, unsigned short* __restrict__ yb,
    float* __restrict__ stats) {
  int bid = blockIdx.x;
  int bs = bid >> 8;               // sample
  int pt = bid & 255;              // pixel tile (64 wide)
  int p0 = pt * 64;
  int tid = threadIdx.x;
  int lane = tid & 63;
  int wave = tid >> 6;             // 0..7 -> o rows wave*32..+31

  // union: B panel 8 x [64p][32c] bf16 = 32 KB, then yt bounce 8x32x72x2 = 36.9 KB
  __shared__ __align__(16) unsigned char smem[8 * 32 * 72 * 2];
  unsigned short* Bp = (unsigned short*)smem;

  // --- staging mapping (rule #21: linear LDS dest, inverse-swizzled source)
  // LDS slot t*16B of subtile: p = t>>2, element slot j = t&3 (8 c each);
  // content c-chunk = j ^ SWZ(p)  ->  element e holds c = e ^ (SWZ(p)<<3).
  int half = tid >> 8;             // waves 0-3: even subtiles; 4-7: odd
  int t = tid & 255;
  int sp = t >> 2;
  int sj = (t & 3) ^ SWZ(sp);
  const unsigned short* bsrc =
      fbT + ((size_t)bs * HWSZ + p0 + sp) * 256 + sj * 8;
  unsigned short* bdst = Bp + (size_t)t * 8;

  // --- A fragments: MB = wave*2 + mb, all K upfront (L2-resident ap)
  const unsigned short* apl = ap + (size_t)(wave * 2) * 4096 + lane * 8;
  short8 af[2][8];
#pragma unroll
  for (int mb = 0; mb < 2; ++mb)
#pragma unroll
    for (int kb = 0; kb < 8; ++kb)
      af[mb][kb] = *(const short8*)(apl + mb * 4096 + kb * 512);
  asm volatile("" ::: "memory");             // pin A-loads above staging
  __builtin_amdgcn_sched_barrier(0);
#pragma unroll
  for (int s = 0; s < 4; ++s) {              // B-subtiles in ascending order
    int sub = 2 * s + half;
    gload_lds16(bsrc + sub * 32, bdst + (size_t)sub * 2048);
    __builtin_amdgcn_sched_barrier(0);
  }

  f32x4 acc[2][4];
#pragma unroll
  for (int mb = 0; mb < 2; ++mb)
#pragma unroll
    for (int nb = 0; nb < 4; ++nb) acc[mb][nb] = (f32x4){0.f, 0.f, 0.f, 0.f};

  // LDS read offsets (elements), r4-proven swizzled mapping
  int pofs[4], cofs[4];
#pragma unroll
  for (int nb = 0; nb < 4; ++nb) {
    int pp = nb * 16 + (lane & 15);
    pofs[nb] = pp * 32;
    cofs[nb] = ((lane >> 4) * 8) ^ (SWZ(pp) << 3);
  }

#pragma unroll
  for (int kb = 0; kb < 8; ++kb) {
    asm volatile("s_waitcnt vmcnt(%0)" :: "i"(3 - (kb >> 1)) : "memory");
    __builtin_amdgcn_s_barrier();
    __builtin_amdgcn_sched_barrier(0);
    const unsigned short* Bk = Bp + kb * 2048;
    short8 bfr[4];
#pragma unroll
    for (int nb = 0; nb < 4; ++nb)
      bfr[nb] = *(const short8*)(Bk + pofs[nb] + cofs[nb]);
#pragma unroll
    for (int mb = 0; mb < 2; ++mb)
#pragma unroll
      for (int nb = 0; nb < 4; ++nb)
        acc[mb][nb] = __builtin_amdgcn_mfma_f32_16x16x32_bf16(
            af[mb][kb], bfr[nb], acc[mb][nb], 0, 0, 0);
  }

  __syncthreads();   // full fence: panel dead, reuse LDS as bounce

  // ---- epilogue: bias, GN partial sums, bounce, coalesced stores
  // C/D layout: col(p) = lane&15, row(o) = (lane>>4)*4 + reg
  unsigned short* yt = (unsigned short*)smem + (size_t)wave * (32 * 72);
  float psum = 0.f, psq = 0.f;
  int orl = (lane >> 4) * 4;
  int pl = lane & 15;
#pragma unroll
  for (int mb = 0; mb < 2; ++mb) {
#pragma unroll
    for (int r = 0; r < 4; ++r) {
      int ol = mb * 16 + orl + r;
      float pb = proj_b[wave * 32 + ol];
#pragma unroll
      for (int nb = 0; nb < 4; ++nb) {
        float v = acc[mb][nb][r] + pb;
        yt[ol * 72 + pl + nb * 16] = f2bf(v);
        psum += v;
        psq += v * v;
      }
    }
  }
  // wave-private bounce: same-wave ds_write->ds_read ordered by lgkmcnt
  const size_t ybase = (size_t)bs * CC * HWSZ + p0;
#pragma unroll
  for (int k = 0; k < 4; ++k) {
    int idx = k * 64 + lane;
    int ol = idx >> 3, ch = idx & 7;
    uint4 v = *(const uint4*)(yt + ol * 72 + ch * 8);
    *(uint4*)(yb + ybase + (size_t)(wave * 32 + ol) * HWSZ + ch * 8) = v;
  }

#pragma unroll
  for (int off = 32; off > 0; off >>= 1) {
    psum += __shfl_down(psum, off, 64);
    psq += __shfl_down(psq, off, 64);
  }
  if (lane == 0) {
    int gb = bs * 8 + wave;        // wave covers exactly one GN group (32 ch)
    atomicAdd(&stats[gb], psum);
    atomicAdd(&stats[128 + gb], psq);
  }
}

// ---------------------------------------------------------------------------
// K5: GroupNorm affine + exact GELU + residual. Reads bf16 y, writes fp32 out.
// ---------------------------------------------------------------------------
__global__ __launch_bounds__(256) void out_kernel(
    const float* __restrict__ x, const unsigned short* __restrict__ yb,
    const float* __restrict__ stats, const float* __restrict__ gamma,
    const float* __restrict__ beta, float* __restrict__ out) {
  int plane = blockIdx.x;
  int b = plane >> 8, c = plane & 255, g = c >> 5;
  const float inv_n = 1.0f / (32.0f * (float)HWSZ);
  float mean = stats[b * 8 + g] * inv_n;
  float var = stats[128 + b * 8 + g] * inv_n - mean * mean;
  float rstd = rsqrtf(var + EPSV);
  float scale = gamma[c] * rstd;
  float shift = beta[c] - mean * scale;

  const size_t base = (size_t)plane * HWSZ;
  for (int i = threadIdx.x; i < HWSZ / 8; i += 256) {
    uint4 yv = *(const uint4*)(yb + base + 8 * (size_t)i);
    float4 x0 = *(const float4*)(x + base + 8 * (size_t)i);
    float4 x1 = *(const float4*)(x + base + 8 * (size_t)i + 4);
    unsigned int yw[4] = {yv.x, yv.y, yv.z, yv.w};
    float r[8];
    float xr[8] = {x0.x, x0.y, x0.z, x0.w, x1.x, x1.y, x1.z, x1.w};
#pragma unroll
    for (int k = 0; k < 8; ++k) {
      unsigned int h = (yw[k >> 1] >> ((k & 1) * 16)) & 0xffffu;
      float t = bf2f(h) * scale + shift;
      float ge = 0.5f * t * (1.0f + erff(t * 0.70710678118654752f));
      r[k] = ge + xr[k];
    }
    *(float4*)(out + base + 8 * (size_t)i) = make_float4(r[0], r[1], r[2], r[3]);
    *(float4*)(out + base + 8 * (size_t)i + 4) = make_float4(r[4], r[5], r[6], r[7]);
  }
}

// ---------------------------------------------------------------------------
extern "C" void kernel_launch(void* const* d_in, const int* in_sizes, int n_in,
                              void* d_out, int out_size, void* d_ws, size_t ws_size,
                              hipStream_t stream) {
  const float* x      = (const float*)d_in[0];
  const float* fbank  = (const float*)d_in[1];   // [NF,1,7,7]
  const float* sel_w  = (const float*)d_in[2];   // [NF,C]
  const float* sel_b  = (const float*)d_in[3];   // [NF]
  const float* proj_w = (const float*)d_in[4];   // [C,C,1,1]
  const float* proj_b = (const float*)d_in[5];   // [C]
  const float* gamma  = (const float*)d_in[6];   // [C]
  const float* beta   = (const float*)d_in[7];   // [C]
  float* out = (float*)d_out;

  // ws layout: buf0 bf16 [B*C*HW] (fb, later reused as yb) |
  //            buf1 bf16 [B*C*HW] (fbT) | ap bf16 [65536] | f32 smalls
  unsigned short* fb  = (unsigned short*)d_ws;   // dwconv out; dead after transpose
  unsigned short* yb  = fb;                      // gemm y output reuses fb space
  unsigned short* fbT = fb + (size_t)BB * CC * HWSZ;
  unsigned short* apk = fbT + (size_t)BB * CC * HWSZ;
  float* pooled   = (float*)(apk + 65536);
  float* combined = pooled + BB * CC;
  float* stats    = combined + BB * 64;

  hipLaunchKernelGGL(pack_a_kernel, dim3(256), dim3(256), 0, stream, proj_w, apk);
  hipLaunchKernelGGL(pool_kernel, dim3(BB * CC), dim3(256), 0, stream, x, pooled);
  hipLaunchKernelGGL(selector_kernel, dim3(1), dim3(256), 0, stream,
                     pooled, sel_w, sel_b, fbank, combined, stats);
  hipLaunchKernelGGL(dwconv_kernel, dim3(BB * CC, HH / TR), dim3(256), 0, stream,
                     x, combined, fb);
  hipLaunchKernelGGL(transpose_kernel, dim3(BB * 4 * 256), dim3(256), 0, stream,
                     fb, fbT);
  hipLaunchKernelGGL(gemm_kernel, dim3(BB * 256), dim3(512), 0, stream,
                     fbT, apk, proj_b, yb, stats);
  hipLaunchKernelGGL(out_kernel, dim3(BB * CC), dim3(256), 0, stream,
                     x, yb, stats, gamma, beta, out);
}